// Round 14
// baseline (291.592 us; speedup 1.0000x reference)
//
#include <hip/hip_runtime.h>

#define NN 50000
#define NE 800000
#define DIMH 128
#define NGRAPH 64
#define NTILES 3125          // 50000 / 16
#define GEMM_BLOCKS 1563     // 4 waves/block; tasks = 2 halves x 3125 tiles = 6250
#define NBIN 196             // dst >> 8
#define BCAP 8064            // staging capacity per bin (max load ~4.4K)
#define SL_F 800000          // floats per feature-slice (NN*16)

typedef __attribute__((ext_vector_type(8))) short bf16x8;
typedef __attribute__((ext_vector_type(4))) float f32x4;

__device__ __forceinline__ unsigned short f2b(float f) {
  unsigned int b = __float_as_uint(f);
  unsigned int r = (b + 0x7FFFu + ((b >> 16) & 1u)) >> 16;  // RNE
  return (unsigned short)r;
}

// 8 consecutive fp32 -> bf16x8 fragment (deterministic rounding at use site)
__device__ __forceinline__ bf16x8 ld8(const float* p) {
  float4 v0 = *(const float4*)p;
  float4 v1 = *(const float4*)(p + 4);
  bf16x8 r;
  r[0] = (short)f2b(v0.x); r[1] = (short)f2b(v0.y);
  r[2] = (short)f2b(v0.z); r[3] = (short)f2b(v0.w);
  r[4] = (short)f2b(v1.x); r[5] = (short)f2b(v1.y);
  r[6] = (short)f2b(v1.z); r[7] = (short)f2b(v1.w);
  return r;
}

// ---------------- binned compact-CSR build ----------------

__global__ __launch_bounds__(256) void bin_scatter_kernel(const int* __restrict__ src,
                                                          const int* __restrict__ dst,
                                                          int* __restrict__ gcnt,
                                                          int2* __restrict__ staging) {
  __shared__ int hist[NBIN];
  __shared__ int base[NBIN];
  int tid = threadIdx.x;
  for (int i = tid; i < NBIN; i += 256) hist[i] = 0;
  __syncthreads();
  int e0 = blockIdx.x * 2048;
  int2 ed[8];
  int bin[8], rank[8];
#pragma unroll
  for (int k = 0; k < 8; ++k) {
    int e = e0 + k * 256 + tid;
    bin[k] = 0; rank[k] = 0; ed[k] = make_int2(0, 0);
    if (e < NE) {
      ed[k].x = src[e]; ed[k].y = dst[e];
      bin[k] = ed[k].y >> 8;
      rank[k] = atomicAdd(&hist[bin[k]], 1);
    }
  }
  __syncthreads();
  for (int i = tid; i < NBIN; i += 256) base[i] = atomicAdd(&gcnt[i], hist[i]);
  __syncthreads();
#pragma unroll
  for (int k = 0; k < 8; ++k) {
    int e = e0 + k * 256 + tid;
    if (e < NE) staging[bin[k] * BCAP + base[bin[k]] + rank[k]] = ed[k];
  }
}

// one block per bin; row starts rounded to EVEN so agg's int2 index loads are
// 8B-aligned.
__global__ __launch_bounds__(256) void bin_fill_kernel(const int2* __restrict__ staging,
                                                       const int* __restrict__ gcnt,
                                                       int* __restrict__ adj,
                                                       int* __restrict__ row_ptr,
                                                       int* __restrict__ cnt,
                                                       int* __restrict__ alloc) {
  __shared__ int hdeg[256], loc[256], c2[256];
  __shared__ int sbase;
  int b = blockIdx.x;
  int tid = threadIdx.x;
  hdeg[tid] = 0; c2[tid] = 0;
  __syncthreads();
  int n = gcnt[b];
  for (int i = tid; i < n; i += 256)
    atomicAdd(&hdeg[staging[b * BCAP + i].y & 255], 1);
  __syncthreads();
  int v = hdeg[tid];
  int va = (v + 1) & ~1;  // even-aligned allocation
  loc[tid] = va;
  __syncthreads();
  for (int off = 1; off < 256; off <<= 1) {
    int t = (tid >= off) ? loc[tid - off] : 0;
    __syncthreads();
    loc[tid] += t;
    __syncthreads();
  }
  if (tid == 255) sbase = atomicAdd(alloc, loc[255]);
  __syncthreads();
  int excl = loc[tid] - va;
  int node = b * 256 + tid;
  if (node < NN) { row_ptr[node] = sbase + excl; cnt[node] = v; }
  loc[tid] = excl;
  __syncthreads();
  for (int i = tid; i < n; i += 256) {
    int2 e = staging[b * BCAP + i];
    int local = e.y & 255;
    int r = atomicAdd(&c2[local], 1);
    adj[sbase + loc[local] + r] = e.x;
  }
}

// ---------------- prep: weight transposes + v2/s2 + out init + counters ----------------

struct WPtrs { const float* w[6]; const float* b_out; const float* b2_last;
               const float* w_out; };

__global__ __launch_bounds__(256) void prep_kernel(WPtrs ptrs, unsigned short* __restrict__ wt,
                                                   float* __restrict__ out,
                                                   int* __restrict__ gcnt,
                                                   int* __restrict__ alloc,
                                                   float* __restrict__ v2,
                                                   float* __restrict__ s2) {
  int i = blockIdx.x * 256 + threadIdx.x;  // 6*16384 elems, m uniform per block
  int m = i >> 14;
  int idx = i & 16383;
  int c = idx >> 7, k = idx & 127;
  wt[m * 16384 + idx] = f2b(ptrs.w[m][k * DIMH + c]);
  if (i < NGRAPH) out[i] = ptrs.b_out[0];
  if (i < NBIN) gcnt[i] = 0;
  if (i == NBIN) *alloc = 0;
  if (i < DIMH) {  // v2[k] = sum_c W2_l2[k][c] * w_out[256+c]  (4-way ILP)
    const float* w2r = ptrs.w[5] + i * DIMH;
    const float* wo = ptrs.w_out + 2 * DIMH;
    float s0 = 0.f, s1 = 0.f, sa = 0.f, sb = 0.f;
#pragma unroll 4
    for (int cc = 0; cc < DIMH; cc += 4) {
      s0 += w2r[cc] * wo[cc];
      s1 += w2r[cc + 1] * wo[cc + 1];
      sa += w2r[cc + 2] * wo[cc + 2];
      sb += w2r[cc + 3] * wo[cc + 3];
    }
    v2[i] = (s0 + s1) + (sa + sb);
  }
  if (i == DIMH) {  // s2 = dot(b2_l2, w_out[256:])
    const float* wo = ptrs.w_out + 2 * DIMH;
    float s0 = 0.f, s1 = 0.f, sa = 0.f, sb = 0.f;
#pragma unroll 4
    for (int cc = 0; cc < DIMH; cc += 4) {
      s0 += ptrs.b2_last[cc] * wo[cc];
      s1 += ptrs.b2_last[cc + 1] * wo[cc + 1];
      sa += ptrs.b2_last[cc + 2] * wo[cc + 2];
      sb += ptrs.b2_last[cc + 3] * wo[cc + 3];
    }
    *s2 = (s0 + s1) + (sa + sb);
  }
}

// h (row-major fp32) -> sliced fp32 [slice][node][16f] (pure permutation, no rounding)
__global__ void convh_kernel(const float* __restrict__ h, float4* __restrict__ Hs) {
  int t = blockIdx.x * 256 + threadIdx.x;  // NN*32 float4 groups
  if (t >= NN * 32) return;
  int node = t >> 5;
  int q = t & 31;            // feat group: feats q*4..q*4+3
  float4 v = *(const float4*)&h[node * DIMH + q * 4];
  Hs[(q >> 2) * (SL_F / 4) + node * 4 + (q & 3)] = v;
}

// ---------------- aggregation: sliced fp32, XCD-affine, deep-ILP ----------------
// slice = blockIdx & 7 (L2-resident 3.2MB column per XCD). 4 lanes/node,
// float4 (4 feats)/lane; unroll 8 edges -> 8 feature loads in flight.
// fp32 accumulate + fp32 store: ordering noise at fp32 ulp only.
__global__ __launch_bounds__(256) void agg_kernel(const float4* __restrict__ Hs,
                                                  const int* __restrict__ row_ptr,
                                                  const int* __restrict__ cnt,
                                                  const int* __restrict__ adj,
                                                  float4* __restrict__ Zs) {
  int bid = blockIdx.x;
  int slice = bid & 7;
  int nb = bid >> 3;
  int tid = threadIdx.x;
  int node = nb * 64 + (tid >> 2);
  int l4 = tid & 3;
  if (node >= NN) return;
  const float4* hp = Hs + slice * (SL_F / 4);
  int start = row_ptr[node];
  int c = cnt[node];
  float4 own = hp[node * 4 + l4];
  float a0 = own.x, a1 = own.y, a2 = own.z, a3 = own.w;
  int j = 0;
  for (; j + 8 <= c; j += 8) {
    int2 i01 = *(const int2*)(adj + start + j);
    int2 i23 = *(const int2*)(adj + start + j + 2);
    int2 i45 = *(const int2*)(adj + start + j + 4);
    int2 i67 = *(const int2*)(adj + start + j + 6);
    float4 u0 = hp[i01.x * 4 + l4];
    float4 u1 = hp[i01.y * 4 + l4];
    float4 u2 = hp[i23.x * 4 + l4];
    float4 u3 = hp[i23.y * 4 + l4];
    float4 u4 = hp[i45.x * 4 + l4];
    float4 u5 = hp[i45.y * 4 + l4];
    float4 u6 = hp[i67.x * 4 + l4];
    float4 u7 = hp[i67.y * 4 + l4];
    a0 += u0.x; a1 += u0.y; a2 += u0.z; a3 += u0.w;
    a0 += u1.x; a1 += u1.y; a2 += u1.z; a3 += u1.w;
    a0 += u2.x; a1 += u2.y; a2 += u2.z; a3 += u2.w;
    a0 += u3.x; a1 += u3.y; a2 += u3.z; a3 += u3.w;
    a0 += u4.x; a1 += u4.y; a2 += u4.z; a3 += u4.w;
    a0 += u5.x; a1 += u5.y; a2 += u5.z; a3 += u5.w;
    a0 += u6.x; a1 += u6.y; a2 += u6.z; a3 += u6.w;
    a0 += u7.x; a1 += u7.y; a2 += u7.z; a3 += u7.w;
  }
  for (; j + 2 <= c; j += 2) {
    int2 i01 = *(const int2*)(adj + start + j);
    float4 u0 = hp[i01.x * 4 + l4];
    float4 u1 = hp[i01.y * 4 + l4];
    a0 += u0.x; a1 += u0.y; a2 += u0.z; a3 += u0.w;
    a0 += u1.x; a1 += u1.y; a2 += u1.z; a3 += u1.w;
  }
  if (j < c) {
    float4 u = hp[adj[start + j] * 4 + l4];
    a0 += u.x; a1 += u.y; a2 += u.z; a3 += u.w;
  }
  Zs[slice * (SL_F / 4) + node * 4 + l4] = make_float4(a0, a1, a2, a3);
}

// ---------------- GEMM kernels: one 16-row x 64-col tile per wave; 6252 waves;
// W-half register-resident (bf16); A built fp32->bf16 inline; fp32 I/O. --------

// GEMM1: Y1 = relu(Z @ W1 + b1). No barriers.
__global__ __launch_bounds__(256) void gemm1_kernel(const float* __restrict__ X,
                                                    const unsigned short* __restrict__ W1t,
                                                    const float* __restrict__ b1,
                                                    float* __restrict__ Y1) {
  int tid = threadIdx.x;
  int gw = blockIdx.x * 4 + (tid >> 6);
  int lane = tid & 63;
  int half = gw & 1;
  int rt = gw >> 1;
  if (rt >= NTILES) return;
  int l15 = lane & 15;
  int g = lane >> 4;
  const float* xp = X + (g >> 1) * SL_F + (g & 1) * 8 + (rt * 16 + l15) * 16;

  bf16x8 a[4];
#pragma unroll
  for (int kt = 0; kt < 4; ++kt) a[kt] = ld8(xp + 2 * kt * SL_F);

  bf16x8 fb[4][4];
  const unsigned short* wb = W1t + (half * 64 + l15) * DIMH + g * 8;
#pragma unroll
  for (int n = 0; n < 4; ++n)
#pragma unroll
    for (int kt = 0; kt < 4; ++kt)
      fb[n][kt] = *(const bf16x8*)(wb + n * 16 * DIMH + kt * 32);
  float bv[4];
#pragma unroll
  for (int n = 0; n < 4; ++n) bv[n] = b1[half * 64 + n * 16 + l15];

#pragma unroll
  for (int n = 0; n < 4; ++n) {
    f32x4 acc = (f32x4){0.f, 0.f, 0.f, 0.f};
#pragma unroll
    for (int kt = 0; kt < 4; ++kt)
      acc = __builtin_amdgcn_mfma_f32_16x16x32_bf16(a[kt], fb[n][kt], acc, 0, 0, 0);
    int sl = 4 * half + n;  // output col slice
#pragma unroll
    for (int r = 0; r < 4; ++r) {
      float f = fmaxf(acc[r] + bv[n], 0.f);
      Y1[sl * SL_F + (rt * 16 + 4 * g + r) * 16 + l15] = f;
    }
  }
}

// GEMM2: Y = Y1 @ W2 + b2 (fp32 sliced store) + fused per-graph readout.
__global__ __launch_bounds__(256) void gemm2_kernel(const float* __restrict__ X,
                                                    const unsigned short* __restrict__ W2t,
                                                    const float* __restrict__ b2,
                                                    float* __restrict__ Y,
                                                    const int* __restrict__ gids,
                                                    const float* __restrict__ wout,
                                                    float* __restrict__ gout) {
  __shared__ float s_gout[NGRAPH];
  int tid = threadIdx.x;
  if (tid < NGRAPH) s_gout[tid] = 0.f;
  __syncthreads();

  int gw = blockIdx.x * 4 + (tid >> 6);
  int lane = tid & 63;
  int half = gw & 1;
  int rt = gw >> 1;
  int l15 = lane & 15;
  int g = lane >> 4;

  if (rt < NTILES) {
    const float* xp = X + (g >> 1) * SL_F + (g & 1) * 8 + (rt * 16 + l15) * 16;
    bf16x8 a[4];
#pragma unroll
    for (int kt = 0; kt < 4; ++kt) a[kt] = ld8(xp + 2 * kt * SL_F);

    bf16x8 fb[4][4];
    const unsigned short* wb = W2t + (half * 64 + l15) * DIMH + g * 8;
#pragma unroll
    for (int n = 0; n < 4; ++n)
#pragma unroll
      for (int kt = 0; kt < 4; ++kt)
        fb[n][kt] = *(const bf16x8*)(wb + n * 16 * DIMH + kt * 32);
    float bv[4], wov[4];
#pragma unroll
    for (int n = 0; n < 4; ++n) {
      int col = half * 64 + n * 16 + l15;
      bv[n] = b2[col];
      wov[n] = wout[col];
    }

    float pr[4] = {0.f, 0.f, 0.f, 0.f};
#pragma unroll
    for (int n = 0; n < 4; ++n) {
      f32x4 acc = (f32x4){0.f, 0.f, 0.f, 0.f};
#pragma unroll
      for (int kt = 0; kt < 4; ++kt)
        acc = __builtin_amdgcn_mfma_f32_16x16x32_bf16(a[kt], fb[n][kt], acc, 0, 0, 0);
      int sl = 4 * half + n;
#pragma unroll
      for (int r = 0; r < 4; ++r) {
        float f = acc[r] + bv[n];
        Y[sl * SL_F + (rt * 16 + 4 * g + r) * 16 + l15] = f;
        pr[r] += f * wov[n];
      }
    }
#pragma unroll
    for (int r = 0; r < 4; ++r) {
#pragma unroll
      for (int off = 1; off < 16; off <<= 1) pr[r] += __shfl_xor(pr[r], off, 64);
    }
    if (l15 == 0) {
#pragma unroll
      for (int r = 0; r < 4; ++r)
        atomicAdd(&s_gout[gids[rt * 16 + 4 * g + r]], pr[r]);
    }
  }

  __syncthreads();
  if (tid < NGRAPH) {
    float v = s_gout[tid];
    if (v != 0.f) atomicAdd(&gout[tid], v);
  }
}

// GEMM last (layer 2): out[g] += dot(relu(Z W1 + b1), v2) + s2. No Y store.
__global__ __launch_bounds__(256) void gemm_last_kernel(const float* __restrict__ X,
                                                        const unsigned short* __restrict__ W1t,
                                                        const float* __restrict__ b1,
                                                        const int* __restrict__ gids,
                                                        float* __restrict__ gout,
                                                        const float* __restrict__ v2,
                                                        const float* __restrict__ s2p) {
  __shared__ float s_gout[NGRAPH];
  int tid = threadIdx.x;
  if (tid < NGRAPH) s_gout[tid] = 0.f;
  __syncthreads();

  int gw = blockIdx.x * 4 + (tid >> 6);
  int lane = tid & 63;
  int half = gw & 1;
  int rt = gw >> 1;
  int l15 = lane & 15;
  int g = lane >> 4;

  if (rt < NTILES) {
    const float* xp = X + (g >> 1) * SL_F + (g & 1) * 8 + (rt * 16 + l15) * 16;
    bf16x8 a[4];
#pragma unroll
    for (int kt = 0; kt < 4; ++kt) a[kt] = ld8(xp + 2 * kt * SL_F);

    bf16x8 fb[4][4];
    const unsigned short* wb = W1t + (half * 64 + l15) * DIMH + g * 8;
#pragma unroll
    for (int n = 0; n < 4; ++n)
#pragma unroll
      for (int kt = 0; kt < 4; ++kt)
        fb[n][kt] = *(const bf16x8*)(wb + n * 16 * DIMH + kt * 32);
    float bv[4], v2v[4];
#pragma unroll
    for (int n = 0; n < 4; ++n) {
      int col = half * 64 + n * 16 + l15;
      bv[n] = b1[col];
      v2v[n] = v2[col];
    }
    float s2v = (half == 0) ? *s2p : 0.f;

    float pr[4] = {0.f, 0.f, 0.f, 0.f};
#pragma unroll
    for (int n = 0; n < 4; ++n) {
      f32x4 acc = (f32x4){0.f, 0.f, 0.f, 0.f};
#pragma unroll
      for (int kt = 0; kt < 4; ++kt)
        acc = __builtin_amdgcn_mfma_f32_16x16x32_bf16(a[kt], fb[n][kt], acc, 0, 0, 0);
#pragma unroll
      for (int r = 0; r < 4; ++r)
        pr[r] += fmaxf(acc[r] + bv[n], 0.f) * v2v[n];
    }
#pragma unroll
    for (int r = 0; r < 4; ++r) {
#pragma unroll
      for (int off = 1; off < 16; off <<= 1) pr[r] += __shfl_xor(pr[r], off, 64);
    }
    if (l15 == 0) {
#pragma unroll
      for (int r = 0; r < 4; ++r)
        atomicAdd(&s_gout[gids[rt * 16 + 4 * g + r]], pr[r] + s2v);
    }
  }

  __syncthreads();
  if (tid < NGRAPH) {
    float v = s_gout[tid];
    if (v != 0.f) atomicAdd(&gout[tid], v);
  }
}

// ---------------- launch ----------------

extern "C" void kernel_launch(void* const* d_in, const int* in_sizes, int n_in,
                              void* d_out, int out_size, void* d_ws, size_t ws_size,
                              hipStream_t stream) {
  const float* h = (const float*)d_in[0];
  const int* src = (const int*)d_in[1];
  const int* dst = (const int*)d_in[2];
  const int* gids = (const int*)d_in[3];
  const float* w_out = (const float*)d_in[16];
  const float* b_out = (const float*)d_in[17];
  float* out = (float*)d_out;

  char* base = (char*)d_ws;
  float* buf0 = (float*)(base);                        // 25.6 MB (sliced fp32 io ping)
  float* buf1 = (float*)(base + 25600000);             // 25.6 MB (sliced fp32 io pong)
  float* Zs   = (float*)(base + 51200000);             // 25.6 MB (z, fp32)
  float* Y1   = (float*)(base + 76800000);             // 25.6 MB (inter-GEMM, fp32)
  int2* staging = (int2*)(base + 102400000);           // 12,644,352 B
  int* adj = (int*)(base + 115200000);                 // 3,400,000 B (even-padded)
  int* row_ptr = (int*)(base + 118600064);             // 200,000 B
  int* cnt = (int*)(base + 118800128);                 // 200,000 B
  int* gcnt = (int*)(base + 119000192);                // 784 B
  int* alloc = (int*)(base + 119001024);               // 4 B
  unsigned short* wt = (unsigned short*)(base + 119002048);  // 196,608 B
  float* v2 = (float*)(base + 119198720);              // 512 B
  float* s2 = (float*)(base + 119199232);              // 4 B

  WPtrs ptrs;
  for (int l = 0; l < 3; ++l) {
    ptrs.w[2 * l] = (const float*)d_in[4 + l * 4];
    ptrs.w[2 * l + 1] = (const float*)d_in[6 + l * 4];
  }
  ptrs.b_out = b_out;
  ptrs.b2_last = (const float*)d_in[15];
  ptrs.w_out = w_out;

  prep_kernel<<<384, 256, 0, stream>>>(ptrs, wt, out, gcnt, alloc, v2, s2);
  bin_scatter_kernel<<<(NE + 2047) / 2048, 256, 0, stream>>>(src, dst, gcnt, staging);
  bin_fill_kernel<<<NBIN, 256, 0, stream>>>(staging, gcnt, adj, row_ptr, cnt, alloc);
  convh_kernel<<<(NN * 32 + 255) / 256, 256, 0, stream>>>(h, (float4*)buf0);

  int agg_blocks = 782 * 8;  // ceil(50000/64) node-blocks x 8 slices (bid&7 = slice)

  for (int l = 0; l < 3; ++l) {
    const float* b1 = (const float*)d_in[5 + l * 4];
    const float* b2 = (const float*)d_in[7 + l * 4];
    const float* Hl = (l & 1) ? buf1 : buf0;
    float* Yl = (l & 1) ? buf0 : buf1;
    agg_kernel<<<agg_blocks, 256, 0, stream>>>((const float4*)Hl, row_ptr, cnt, adj,
                                               (float4*)Zs);
    if (l < 2) {
      gemm1_kernel<<<GEMM_BLOCKS, 256, 0, stream>>>(Zs, wt + (2 * l) * 16384, b1, Y1);
      gemm2_kernel<<<GEMM_BLOCKS, 256, 0, stream>>>(Y1, wt + (2 * l + 1) * 16384, b2,
                                                    Yl, gids, w_out + l * DIMH, out);
    } else {
      gemm_last_kernel<<<GEMM_BLOCKS, 256, 0, stream>>>(Zs, wt + (2 * l) * 16384, b1,
                                                        gids, out, v2, s2);
    }
  }
}